// Round 5
// baseline (236.568 us; speedup 1.0000x reference)
//
#include <hip/hip_runtime.h>
#include <hip/hip_fp16.h>

#define N_NODES 50000
#define E_EDGES 800000
#define NTILES  (E_EDGES / 16)        // 50000 exact
#define NB_NODE ((N_NODES + 255) / 256)   // 196
#define NB_EDGE ((E_EDGES + 255) / 256)   // 3125

typedef __attribute__((ext_vector_type(8))) short short8;
typedef __attribute__((ext_vector_type(4))) float floatx4;

// float -> bf16 bits, round-to-nearest-even (used in prep only)
__device__ __forceinline__ short f2bf(float x) {
    union { float f; unsigned u; } v; v.f = x;
    unsigned r = v.u + 0x7FFFu + ((v.u >> 16) & 1u);
    return (short)(r >> 16);
}

// pack bf16x2 (RTZ) from two floats via v_perm_b32: 1 VALU per pair
__device__ __forceinline__ unsigned pk_bf16(float lo, float hi) {
    union { float f; unsigned u; } a, b; a.f = lo; b.f = hi;
    return __builtin_amdgcn_perm(b.u, a.u, 0x07060302u);
}

// Kernel A: per-node LayerNorm+ReLU -> h; out = bias + h @ root; zero cnt[n]
__global__ __launch_bounds__(256) void node_kernel(
    const float* __restrict__ x, const float* __restrict__ gamma,
    const float* __restrict__ beta, const float* __restrict__ root,
    const float* __restrict__ bias, float* __restrict__ h,
    float* __restrict__ out, int* __restrict__ cnt)
{
    int n = blockIdx.x * blockDim.x + threadIdx.x;
    if (n >= N_NODES) return;
    cnt[n] = 0;   // histogram counters for the dst sort (hist runs after, in-stream)
    const float* xr = x + n * 16;
    float xv[16];
    #pragma unroll
    for (int i = 0; i < 4; ++i) ((floatx4*)xv)[i] = ((const floatx4*)xr)[i];
    float mu = 0.f;
    #pragma unroll
    for (int i = 0; i < 16; ++i) mu += xv[i];
    mu *= (1.f / 16.f);
    float var = 0.f;
    #pragma unroll
    for (int i = 0; i < 16; ++i) { float d = xv[i] - mu; var += d * d; }
    var *= (1.f / 16.f);
    float rs = rsqrtf(var + 1e-5f);
    float hv[16];
    #pragma unroll
    for (int i = 0; i < 16; ++i) {
        float t = (xv[i] - mu) * rs * gamma[i] + beta[i];
        hv[i] = t > 0.f ? t : 0.f;
    }
    float* hr = h + n * 16;
    #pragma unroll
    for (int i = 0; i < 4; ++i) ((floatx4*)hr)[i] = ((floatx4*)hv)[i];

    float ov[16];
    #pragma unroll
    for (int o = 0; o < 16; ++o) ov[o] = bias[o];
    #pragma unroll
    for (int i = 0; i < 16; ++i) {
        float hi = hv[i];
        #pragma unroll
        for (int o = 0; o < 16; ++o) ov[o] += hi * root[i * 16 + o];
    }
    float* orow = out + n * 16;
    #pragma unroll
    for (int i = 0; i < 4; ++i) ((floatx4*)orow)[i] = ((floatx4*)ov)[i];
}

// Kernel W: W2t[m][k] = bf16(W2[k][m]), [16][160] bf16 = 5 KB.
__global__ __launch_bounds__(256) void prep_kernel(
    const float* __restrict__ w_edge, const float* __restrict__ b_edge,
    short* __restrict__ w2t)
{
    int t = blockIdx.x * blockDim.x + threadIdx.x;
    if (t >= 16 * 160) return;
    int m = t / 160, k = t % 160;
    float v = 0.f;
    if (k < 128)      v = w_edge[(k >> 4) * 256 + (k & 15) * 16 + m];
    else if (k < 144) v = b_edge[(k - 128) * 16 + m];
    w2t[m * 160 + k] = f2bf(v);
}

// ---- counting sort by dst: hist -> scan (3 kernels) -> scatter ----

__global__ __launch_bounds__(256) void hist_kernel(
    const int* __restrict__ eidx, int* __restrict__ cnt)
{
    int e = blockIdx.x * 256 + threadIdx.x;
    if (e < E_EDGES) atomicAdd(cnt + eidx[E_EDGES + e], 1);
}

// per-block inclusive scan of cnt -> tmp; block totals -> part
__global__ __launch_bounds__(256) void scanA_kernel(
    const int* __restrict__ cnt, int* __restrict__ tmp, int* __restrict__ part)
{
    int i = blockIdx.x * 256 + threadIdx.x;
    int v = (i < N_NODES) ? cnt[i] : 0;
    int lane = threadIdx.x & 63, wv = threadIdx.x >> 6;
    int s = v;
    #pragma unroll
    for (int d = 1; d < 64; d <<= 1) { int t = __shfl_up(s, d, 64); if (lane >= d) s += t; }
    __shared__ int wsum[4];
    if (lane == 63) wsum[wv] = s;
    __syncthreads();
    int base = 0;
    #pragma unroll
    for (int w = 0; w < 3; ++w) if (w < wv) base += wsum[w];
    int incl = s + base;
    if (i < N_NODES) tmp[i] = incl;
    if (threadIdx.x == 255) part[blockIdx.x] = incl;
}

// exclusive scan of the 196 block totals (single block)
__global__ __launch_bounds__(256) void scanB_kernel(
    const int* __restrict__ part, int* __restrict__ partoffs)
{
    int i = threadIdx.x;
    int v = (i < NB_NODE) ? part[i] : 0;
    int lane = threadIdx.x & 63, wv = threadIdx.x >> 6;
    int s = v;
    #pragma unroll
    for (int d = 1; d < 64; d <<= 1) { int t = __shfl_up(s, d, 64); if (lane >= d) s += t; }
    __shared__ int wsum[4];
    if (lane == 63) wsum[wv] = s;
    __syncthreads();
    int base = 0;
    #pragma unroll
    for (int w = 0; w < 3; ++w) if (w < wv) base += wsum[w];
    if (i < NB_NODE) partoffs[i] = s + base - v;   // exclusive
}

// offs[i] = global exclusive scan; cur = consumable copy for scatter
__global__ __launch_bounds__(256) void scanC_kernel(
    const int* __restrict__ tmp, const int* __restrict__ cnt,
    const int* __restrict__ partoffs, int* __restrict__ offs, int* __restrict__ cur)
{
    int i = blockIdx.x * 256 + threadIdx.x;
    if (i < N_NODES) {
        int o = tmp[i] - cnt[i] + partoffs[blockIdx.x];
        offs[i] = o;
        cur[i]  = o;
    }
    if (i == 0) offs[N_NODES] = E_EDGES;
}

// perm[pos] = e, sorted by dst (unstable is fine: aggregation is a sum)
__global__ __launch_bounds__(256) void scatter_kernel(
    const int* __restrict__ eidx, int* __restrict__ cur, int* __restrict__ perm)
{
    int e = blockIdx.x * 256 + threadIdx.x;
    if (e < E_EDGES) {
        int d = eidx[E_EDGES + e];
        int pos = atomicAdd(cur + d, 1);
        perm[pos] = e;
    }
}

// Kernel B: ONE wave per tile of 16 edges (round-2 structure, MFMA unchanged).
// Epilogue: ZERO atomics — plain contiguous f16 stores of msg[e][16].
// Lanes pair adjacent cols via shfl_xor; even lanes store rows 4q,4q+1,
// odd lanes rows 4q+2,4q+3 (2 x 4B store per lane, fully covering the tile).
__global__ __launch_bounds__(256) void edge_kernel(
    const int* __restrict__ eidx, const float* __restrict__ ea,
    const short* __restrict__ w2t, const float* __restrict__ h,
    __half* __restrict__ msg)
{
    const int lane = threadIdx.x & 63;
    const int wid  = threadIdx.x >> 6;
    const int m = lane & 15;   // edge-in-tile for A; output col for C/D and B
    const int q = lane >> 4;   // quad
    const int odd = m & 1;
    const int mlo = m & ~1;

    const int tile = blockIdx.x * 4 + wid;
    if (tile >= NTILES) return;

    const int e   = tile * 16 + m;
    const int src = eidx[e];

    const short* wp = w2t + m * 160 + 8 * q;
    short8 bfrag[5];
    #pragma unroll
    for (int c = 0; c < 5; ++c)
        bfrag[c] = *(const short8*)(wp + 32 * c);

    const float* er = ea + (size_t)e * 8;
    floatx4 ea0 = ((const floatx4*)er)[0];
    floatx4 ea1 = ((const floatx4*)er)[1];

    const float* hr = h + src * 16 + 8 * (q & 1);
    floatx4 h0 = ((const floatx4*)hr)[0];
    floatx4 h1 = ((const floatx4*)hr)[1];
    float hh[8] = {h0.x, h0.y, h0.z, h0.w, h1.x, h1.y, h1.z, h1.w};

    floatx4 acc = {0.f, 0.f, 0.f, 0.f};
    const int hi_t = q >> 1;
    #pragma unroll
    for (int c = 0; c < 4; ++c) {
        float te, to;
        if (c == 0)      { te = ea0.x; to = ea0.y; }
        else if (c == 1) { te = ea0.z; to = ea0.w; }
        else if (c == 2) { te = ea1.x; to = ea1.y; }
        else             { te = ea1.z; to = ea1.w; }
        float s = hi_t ? to : te;
        union { short8 s8; unsigned u[4]; } af;
        #pragma unroll
        for (int p = 0; p < 4; ++p)
            af.u[p] = pk_bf16(s * hh[2 * p], s * hh[2 * p + 1]);
        acc = __builtin_amdgcn_mfma_f32_16x16x32_bf16(af.s8, bfrag[c], acc, 0, 0, 0);
    }
    // chunk 4: z = h[i] for q<2, 0 otherwise (mask the packed words)
    {
        const unsigned msk = (q < 2) ? 0xFFFFFFFFu : 0u;
        union { short8 s8; unsigned u[4]; } af;
        #pragma unroll
        for (int p = 0; p < 4; ++p)
            af.u[p] = pk_bf16(hh[2 * p], hh[2 * p + 1]) & msk;
        acc = __builtin_amdgcn_mfma_f32_16x16x32_bf16(af.s8, bfrag[4], acc, 0, 0, 0);
    }

    // C/D layout: col = m, row = 4q + r (edge index in tile).
    float px[4];
    #pragma unroll
    for (int r = 0; r < 4; ++r)
        px[r] = __shfl_xor(acc[r], 1, 64);
    #pragma unroll
    for (int k = 0; k < 2; ++k) {
        const int r = 2 * odd + k;
        float lo = odd ? px[r] : acc[r];
        float hi = odd ? acc[r] : px[r];
        __half2 v = __floats2half2_rn(lo, hi);
        const int row = 4 * q + 2 * odd + k;
        *(__half2*)(msg + ((size_t)(tile * 16 + row)) * 16 + mlo) = v;
    }
}

// Kernel G: per-node CSR gather-sum of messages (f32 accumulate), out += sum
__global__ __launch_bounds__(256) void agg_kernel(
    const int* __restrict__ offs, const int* __restrict__ perm,
    const __half* __restrict__ msg, float* __restrict__ out)
{
    int n = blockIdx.x * 256 + threadIdx.x;
    if (n >= N_NODES) return;
    int j0 = offs[n], j1 = offs[n + 1];
    float s[16];
    #pragma unroll
    for (int c = 0; c < 16; ++c) s[c] = 0.f;
    for (int j = j0; j < j1; ++j) {
        int e = perm[j];
        union { floatx4 f4; __half2 h2[4]; } a, b;
        const floatx4* mr = (const floatx4*)(msg + (size_t)e * 16);
        a.f4 = mr[0];
        b.f4 = mr[1];
        #pragma unroll
        for (int p = 0; p < 4; ++p) {
            float2 fa = __half22float2(a.h2[p]);
            float2 fb = __half22float2(b.h2[p]);
            s[2 * p]     += fa.x; s[2 * p + 1]     += fa.y;
            s[8 + 2 * p] += fb.x; s[8 + 2 * p + 1] += fb.y;
        }
    }
    float* orow = out + (size_t)n * 16;
    #pragma unroll
    for (int i = 0; i < 4; ++i) {
        floatx4 o = ((floatx4*)orow)[i];
        o.x += s[4 * i]; o.y += s[4 * i + 1]; o.z += s[4 * i + 2]; o.w += s[4 * i + 3];
        ((floatx4*)orow)[i] = o;
    }
}

extern "C" void kernel_launch(void* const* d_in, const int* in_sizes, int n_in,
                              void* d_out, int out_size, void* d_ws, size_t ws_size,
                              hipStream_t stream) {
    const float* x        = (const float*)d_in[0];
    const int*   eidx     = (const int*)d_in[1];
    const float* ea       = (const float*)d_in[2];
    const float* ln_gamma = (const float*)d_in[3];
    const float* ln_beta  = (const float*)d_in[4];
    const float* w_edge   = (const float*)d_in[5];
    const float* b_edge   = (const float*)d_in[6];
    const float* root     = (const float*)d_in[7];
    const float* bias     = (const float*)d_in[8];
    float* out = (float*)d_out;

    // workspace layout (all 16B-aligned):
    // h [3.2MB] | w2t [5KB] | cnt [200KB] | offs [200KB+pad] | cur [200KB]
    // | tmp [200KB] | part [1KB] | partoffs [1KB] | perm [3.2MB] | msg [25.6MB]
    char* p = (char*)d_ws;
    float* h    = (float*)p;  p += (size_t)N_NODES * 16 * 4;
    short* w2t  = (short*)p;  p += 16 * 160 * 2;
    int* cnt    = (int*)p;    p += (size_t)N_NODES * 4;
    int* offs   = (int*)p;    p += (size_t)(N_NODES + 4) * 4;
    int* cur    = (int*)p;    p += (size_t)N_NODES * 4;
    int* tmp    = (int*)p;    p += (size_t)N_NODES * 4;
    int* part   = (int*)p;    p += 256 * 4;
    int* poffs  = (int*)p;    p += 256 * 4;
    int* perm   = (int*)p;    p += (size_t)E_EDGES * 4;
    __half* msg = (__half*)p;

    prep_kernel<<<10, 256, 0, stream>>>(w_edge, b_edge, w2t);
    node_kernel<<<NB_NODE, 256, 0, stream>>>(
        x, ln_gamma, ln_beta, root, bias, h, out, cnt);
    hist_kernel<<<NB_EDGE, 256, 0, stream>>>(eidx, cnt);
    scanA_kernel<<<NB_NODE, 256, 0, stream>>>(cnt, tmp, part);
    scanB_kernel<<<1, 256, 0, stream>>>(part, poffs);
    scanC_kernel<<<NB_NODE, 256, 0, stream>>>(tmp, cnt, poffs, offs, cur);
    scatter_kernel<<<NB_EDGE, 256, 0, stream>>>(eidx, cur, perm);
    edge_kernel<<<(NTILES + 3) / 4, 256, 0, stream>>>(eidx, ea, w2t, h, msg);
    agg_kernel<<<NB_NODE, 256, 0, stream>>>(offs, perm, msg, out);
}

// Round 6
// 148.058 us; speedup vs baseline: 1.5978x; 1.5978x over previous
//
#include <hip/hip_runtime.h>

#define N_NODES 50000
#define E_EDGES 800000
#define NTILES  (E_EDGES / 16)   // 50000 exact
#define NPART   8                // partial accumulators (spread atomic lines)

typedef __attribute__((ext_vector_type(8))) short short8;
typedef __attribute__((ext_vector_type(4))) float floatx4;

// float -> bf16 bits, round-to-nearest-even (used in prep only)
__device__ __forceinline__ short f2bf(float x) {
    union { float f; unsigned u; } v; v.f = x;
    unsigned r = v.u + 0x7FFFu + ((v.u >> 16) & 1u);
    return (short)(r >> 16);
}

// pack bf16x2 (RTZ) from two floats via v_perm_b32: 1 VALU per pair
__device__ __forceinline__ unsigned pk_bf16(float lo, float hi) {
    union { float f; unsigned u; } a, b; a.f = lo; b.f = hi;
    return __builtin_amdgcn_perm(b.u, a.u, 0x07060302u);
}

// Kernel A: per-node LayerNorm+ReLU -> h; out = bias + h @ root
__global__ __launch_bounds__(256) void node_kernel(
    const float* __restrict__ x, const float* __restrict__ gamma,
    const float* __restrict__ beta, const float* __restrict__ root,
    const float* __restrict__ bias, float* __restrict__ h,
    float* __restrict__ out)
{
    int n = blockIdx.x * blockDim.x + threadIdx.x;
    if (n >= N_NODES) return;
    const float* xr = x + n * 16;
    float xv[16];
    #pragma unroll
    for (int i = 0; i < 4; ++i) ((floatx4*)xv)[i] = ((const floatx4*)xr)[i];
    float mu = 0.f;
    #pragma unroll
    for (int i = 0; i < 16; ++i) mu += xv[i];
    mu *= (1.f / 16.f);
    float var = 0.f;
    #pragma unroll
    for (int i = 0; i < 16; ++i) { float d = xv[i] - mu; var += d * d; }
    var *= (1.f / 16.f);
    float rs = rsqrtf(var + 1e-5f);
    float hv[16];
    #pragma unroll
    for (int i = 0; i < 16; ++i) {
        float t = (xv[i] - mu) * rs * gamma[i] + beta[i];
        hv[i] = t > 0.f ? t : 0.f;
    }
    float* hr = h + n * 16;
    #pragma unroll
    for (int i = 0; i < 4; ++i) ((floatx4*)hr)[i] = ((floatx4*)hv)[i];

    float ov[16];
    #pragma unroll
    for (int o = 0; o < 16; ++o) ov[o] = bias[o];
    #pragma unroll
    for (int i = 0; i < 16; ++i) {
        float hi = hv[i];
        #pragma unroll
        for (int o = 0; o < 16; ++o) ov[o] += hi * root[i * 16 + o];
    }
    float* orow = out + n * 16;
    #pragma unroll
    for (int i = 0; i < 4; ++i) ((floatx4*)orow)[i] = ((floatx4*)ov)[i];
}

// Kernel W: W2t[m][k] = bf16(W2[k][m]), [16][160] bf16 = 5 KB.
__global__ __launch_bounds__(256) void prep_kernel(
    const float* __restrict__ w_edge, const float* __restrict__ b_edge,
    short* __restrict__ w2t)
{
    int t = blockIdx.x * blockDim.x + threadIdx.x;
    if (t >= 16 * 160) return;
    int m = t / 160, k = t % 160;
    float v = 0.f;
    if (k < 128)      v = w_edge[(k >> 4) * 256 + (k & 15) * 16 + m];
    else if (k < 144) v = b_edge[(k - 128) * 16 + m];
    w2t[m * 160 + k] = f2bf(v);
}

// Kernel B: ONE wave per tile of 16 edges (round-0/2 proven structure).
// Epilogue: f32 atomics into partials[blockIdx&7] — each node's ~16 incoming
// edges split ~2 per partial buffer, cutting the per-cache-line atomic
// serialization chain from 256 ops to ~32 (the round-0/2/4 44-us invariant
// fits a ~400cy same-line RMW recurrence; this attacks exactly that).
__global__ __launch_bounds__(256) void edge_kernel(
    const int* __restrict__ eidx, const float* __restrict__ ea,
    const short* __restrict__ w2t, const float* __restrict__ h,
    float* __restrict__ partials)
{
    const int lane = threadIdx.x & 63;
    const int wid  = threadIdx.x >> 6;
    const int m = lane & 15;   // edge-in-tile for A; output col for C/D and B
    const int q = lane >> 4;   // quad

    const int tile = blockIdx.x * 4 + wid;
    if (tile >= NTILES) return;

    const int e   = tile * 16 + m;
    const int src = eidx[e];
    const int dst = eidx[E_EDGES + e];

    const short* wp = w2t + m * 160 + 8 * q;
    short8 bfrag[5];
    #pragma unroll
    for (int c = 0; c < 5; ++c)
        bfrag[c] = *(const short8*)(wp + 32 * c);

    const float* er = ea + (size_t)e * 8;
    floatx4 ea0 = ((const floatx4*)er)[0];
    floatx4 ea1 = ((const floatx4*)er)[1];

    const float* hr = h + src * 16 + 8 * (q & 1);
    floatx4 h0 = ((const floatx4*)hr)[0];
    floatx4 h1 = ((const floatx4*)hr)[1];
    float hh[8] = {h0.x, h0.y, h0.z, h0.w, h1.x, h1.y, h1.z, h1.w};

    floatx4 acc = {0.f, 0.f, 0.f, 0.f};
    const int hi_t = q >> 1;
    #pragma unroll
    for (int c = 0; c < 4; ++c) {
        float te, to;
        if (c == 0)      { te = ea0.x; to = ea0.y; }
        else if (c == 1) { te = ea0.z; to = ea0.w; }
        else if (c == 2) { te = ea1.x; to = ea1.y; }
        else             { te = ea1.z; to = ea1.w; }
        float s = hi_t ? to : te;
        union { short8 s8; unsigned u[4]; } af;
        #pragma unroll
        for (int p = 0; p < 4; ++p)
            af.u[p] = pk_bf16(s * hh[2 * p], s * hh[2 * p + 1]);
        acc = __builtin_amdgcn_mfma_f32_16x16x32_bf16(af.s8, bfrag[c], acc, 0, 0, 0);
    }
    // chunk 4: z = h[i] for q<2, 0 otherwise (mask the packed words)
    {
        const unsigned msk = (q < 2) ? 0xFFFFFFFFu : 0u;
        union { short8 s8; unsigned u[4]; } af;
        #pragma unroll
        for (int p = 0; p < 4; ++p)
            af.u[p] = pk_bf16(hh[2 * p], hh[2 * p + 1]) & msk;
        acc = __builtin_amdgcn_mfma_f32_16x16x32_bf16(af.s8, bfrag[4], acc, 0, 0, 0);
    }

    // C/D layout: col = m, row = 4q + r (edge index in tile)
    float* part = partials + (size_t)(blockIdx.x & (NPART - 1)) * N_NODES * 16;
    #pragma unroll
    for (int r = 0; r < 4; ++r) {
        int dr = __shfl(dst, 4 * q + r, 64);
        unsafeAtomicAdd(part + (size_t)dr * 16 + m, acc[r]);
    }
}

// Kernel R: out += sum over the 8 partials (f32, 16B-vector per thread)
__global__ __launch_bounds__(256) void reduce_kernel(
    const float* __restrict__ partials, float* __restrict__ out)
{
    int t = blockIdx.x * 256 + threadIdx.x;   // float4-chunk id
    if (t >= N_NODES * 4) return;
    floatx4 s = ((floatx4*)out)[t];
    #pragma unroll
    for (int p = 0; p < NPART; ++p) {
        floatx4 v = ((const floatx4*)(partials + (size_t)p * N_NODES * 16))[t];
        s.x += v.x; s.y += v.y; s.z += v.z; s.w += v.w;
    }
    ((floatx4*)out)[t] = s;
}

extern "C" void kernel_launch(void* const* d_in, const int* in_sizes, int n_in,
                              void* d_out, int out_size, void* d_ws, size_t ws_size,
                              hipStream_t stream) {
    const float* x        = (const float*)d_in[0];
    const int*   eidx     = (const int*)d_in[1];
    const float* ea       = (const float*)d_in[2];
    const float* ln_gamma = (const float*)d_in[3];
    const float* ln_beta  = (const float*)d_in[4];
    const float* w_edge   = (const float*)d_in[5];
    const float* b_edge   = (const float*)d_in[6];
    const float* root     = (const float*)d_in[7];
    const float* bias     = (const float*)d_in[8];
    float* out = (float*)d_out;

    // workspace: h [3.2MB] | w2t [5KB, padded] | partials [8 x 3.2MB = 25.6MB]
    char* p = (char*)d_ws;
    float* h        = (float*)p;  p += (size_t)N_NODES * 16 * 4;
    short* w2t      = (short*)p;  p += 16 * 160 * 2;
    float* partials = (float*)p;

    hipMemsetAsync(partials, 0, (size_t)NPART * N_NODES * 16 * 4, stream);
    prep_kernel<<<10, 256, 0, stream>>>(w_edge, b_edge, w2t);
    node_kernel<<<(N_NODES + 255) / 256, 256, 0, stream>>>(
        x, ln_gamma, ln_beta, root, bias, h, out);
    edge_kernel<<<(NTILES + 3) / 4, 256, 0, stream>>>(eidx, ea, w2t, h, partials);
    reduce_kernel<<<(N_NODES * 4 + 255) / 256, 256, 0, stream>>>(partials, out);
}